// Round 2
// baseline (489.814 us; speedup 1.0000x reference)
//
#include <hip/hip_runtime.h>

#define Bb 8
#define Ll 2048
#define Hh 1024

typedef __bf16 bf16;
typedef signed char i8;
typedef __attribute__((ext_vector_type(8))) __bf16 bf16x8;
typedef __attribute__((ext_vector_type(4))) __bf16 bf16x4;
typedef __attribute__((ext_vector_type(4))) float f32x4;
typedef __attribute__((ext_vector_type(4))) int i32x4;

// quant ranges: x,q in +-6 ; W in +-0.25 ; lo-scale = hi-scale/512 so both
// cross terms share one i32 accumulator (scale products equal).
#define RX 6.0f
#define RW 0.25f

__device__ __forceinline__ void gload16(const void* src, void* dst) {
  __builtin_amdgcn_global_load_lds(
      (const __attribute__((address_space(1))) void*)src,
      (__attribute__((address_space(3))) void*)dst, 16, 0, 0);
}

__device__ __forceinline__ i8 q8(float v, float inv_s) {
  float r = fminf(fmaxf(v * inv_s, -127.f), 127.f);
  return (i8)__float2int_rn(r);
}

// ---------------------------------------------------------------------------
// Split X (f32) -> Xhi (bf16), Xhi8/Xlo8 (i8), XT (bf16, [b][h][l])
// ---------------------------------------------------------------------------
__global__ __launch_bounds__(256) void split_x_k(
    const float* __restrict__ X, bf16* __restrict__ Xhi,
    i8* __restrict__ Xhi8, i8* __restrict__ Xlo8, bf16* __restrict__ XT) {
  __shared__ float tile[64][65];
  const int h0 = blockIdx.x << 6, l0 = blockIdx.y << 6, b = blockIdx.z;
  const int t = threadIdx.x;
  const int c = t & 63, r0 = t >> 6;
  const long base = ((long)b * Ll + l0) * Hh + h0;
  const float* Xb = X + base;
  bf16* XhiB = Xhi + base;
  i8* Xhi8B = Xhi8 + base;
  i8* Xlo8B = Xlo8 + base;
  const float ih = 127.f / RX, il = 127.f * 512.f / RX;
#pragma unroll
  for (int i = 0; i < 16; ++i) {
    int row = (i << 2) + r0;
    long o = (long)row * Hh + c;
    float x = Xb[o];
    bf16 hi = (bf16)x;
    float hf = (float)hi;
    XhiB[o] = hi;
    Xhi8B[o] = q8(hf, ih);
    Xlo8B[o] = q8(x - hf, il);
    tile[row][c] = x;
  }
  __syncthreads();
  bf16* XTB = XT + ((long)b * Hh + h0) * Ll + l0;
#pragma unroll
  for (int i = 0; i < 16; ++i) {
    int row = (i << 2) + r0;  // h index
    XTB[(long)row * Ll + c] = (bf16)tile[c][row];
  }
}

// ---------------------------------------------------------------------------
// Split W (f32 [o][h]) -> Whi (bf16), Whi8/Wlo8 (i8)
// ---------------------------------------------------------------------------
__global__ __launch_bounds__(256) void split_w_k(
    const float* __restrict__ W, bf16* __restrict__ Whi,
    i8* __restrict__ Whi8, i8* __restrict__ Wlo8) {
  int i = blockIdx.x * 256 + threadIdx.x;
  float4 v = ((const float4*)W)[i];
  const float ih = 127.f / RW, il = 127.f * 512.f / RW;
  float vv[4] = {v.x, v.y, v.z, v.w};
#pragma unroll
  for (int j = 0; j < 4; ++j) {
    float x = vv[j];
    bf16 hi = (bf16)x;
    float hf = (float)hi;
    Whi[i * 4 + j] = hi;
    Whi8[i * 4 + j] = q8(hf, ih);
    Wlo8[i * 4 + j] = q8(x - hf, il);
  }
}

// ---------------------------------------------------------------------------
// NT GEMM, 128x128 tile, BK=64, 4 waves.
// MODE 0: plain bf16 (1 pass). MODE 1: hi*hi in bf16 + cross terms
// (hi*lo + lo*hi) in one shared-scale i8 accumulator via mfma_i32_16x16x64_i8.
// EPI 0: bias add, store Qhi bf16 + Qhi8/Qlo8 i8.  EPI 1: relu f32.
// EPI 2: f32.
// LDS: bf16 planes [128][64] + i8 planes [128][128B] (hi|lo per row),
// all 8-slot (16B) XOR-swizzled; gload_lds dest linear, source pre-swizzled.
// ---------------------------------------------------------------------------
template <int EPI, int MODE>
__global__ __launch_bounds__(256, 2) void gemm_nt(
    const bf16* __restrict__ Ahi, const i8* __restrict__ Ahi8,
    const i8* __restrict__ Alo8, const bf16* __restrict__ Bhi,
    const i8* __restrict__ Bhi8, const i8* __restrict__ Blo8, int N, int K,
    long sA_, long sB_, long sC_, float C8, float* __restrict__ outF,
    bf16* __restrict__ outQhi, i8* __restrict__ outQhi8,
    i8* __restrict__ outQlo8, const float* __restrict__ bias) {
  constexpr int LDSB = MODE ? 65536 : 32768;
  __shared__ char lds[LDSB];
  bf16* AH = (bf16*)lds;          // [128][64] bf16
  bf16* BH = (bf16*)(lds + 16384);
  char* AI = lds + 32768;         // [128][128B] i8: slots 0-3 hi, 4-7 lo
  char* BI = lds + 49152;

  const int b = blockIdx.z;
  const int m0 = blockIdx.y * 128;
  const int n0 = blockIdx.x * 128;
  const bf16* Ah = Ahi + (long)b * sA_ + (long)m0 * K;
  const bf16* Bh = Bhi + (long)b * sB_ + (long)n0 * K;

  const int t = threadIdx.x;
  const int lane = t & 63;
  const int w = t >> 6;
  const int wr = (w >> 1) * 64, wc = (w & 1) * 64;
  const int g = lane >> 4;
  const int fr = lane & 15;

  f32x4 acc[4][4];
  i32x4 acc8[4][4];
#pragma unroll
  for (int m = 0; m < 4; ++m)
#pragma unroll
    for (int n = 0; n < 4; ++n) {
      acc[m][n] = {0.f, 0.f, 0.f, 0.f};
      if constexpr (MODE) acc8[m][n] = {0, 0, 0, 0};
    }

  // staging precompute. bf16 planes: chunk c=p*256+t -> LDS bytes [c*16,+16)
  // = row c>>3, phys slot c&7; source column slot = phys ^ (row&7).
  const bf16 *sAh[4], *sBh[4];
  const i8 *sA8[4], *sB8[4];
#pragma unroll
  for (int p = 0; p < 4; ++p) {
    int c = p * 256 + t;
    int row = c >> 3;
    int l = (c & 7) ^ (row & 7);
    sAh[p] = Ah + (long)row * K + l * 8;
    sBh[p] = Bh + (long)row * K + l * 8;
    if constexpr (MODE) {
      const i8* a8 = (l < 4) ? Ahi8 : Alo8;
      const i8* b8 = (l < 4) ? Bhi8 : Blo8;
      sA8[p] = a8 + (long)b * sA_ + ((long)(m0 + row)) * K + (l & 3) * 16;
      sB8[p] = b8 + (long)b * sB_ + ((long)(n0 + row)) * K + (l & 3) * 16;
    }
  }

  for (int kt = 0; kt < K; kt += 64) {
#pragma unroll
    for (int p = 0; p < 4; ++p) {
      const int d = (p * 256 + t) * 16;
      gload16(sAh[p] + kt, (char*)AH + d);
      gload16(sBh[p] + kt, (char*)BH + d);
      if constexpr (MODE) {
        gload16(sA8[p] + kt, AI + d);
        gload16(sB8[p] + kt, BI + d);
      }
    }
    __syncthreads();
    // bf16 hi*hi
#pragma unroll
    for (int ks = 0; ks < 2; ++ks) {
      bf16x8 ah[4], bh[4];
#pragma unroll
      for (int m = 0; m < 4; ++m) {
        int row = wr + m * 16 + fr;
        ah[m] = *(const bf16x8*)&AH[row * 64 + ((((ks << 2) | g) ^ (row & 7)) << 3)];
      }
#pragma unroll
      for (int n = 0; n < 4; ++n) {
        int row = wc + n * 16 + fr;
        bh[n] = *(const bf16x8*)&BH[row * 64 + ((((ks << 2) | g) ^ (row & 7)) << 3)];
      }
#pragma unroll
      for (int m = 0; m < 4; ++m)
#pragma unroll
        for (int n = 0; n < 4; ++n)
          acc[m][n] = __builtin_amdgcn_mfma_f32_16x16x32_bf16(ah[m], bh[n],
                                                              acc[m][n], 0, 0, 0);
    }
    // i8 cross terms: hi*lo + lo*hi, shared scale
    if constexpr (MODE) {
      i32x4 ah8[4], al8[4], bh8[4], bl8[4];
#pragma unroll
      for (int m = 0; m < 4; ++m) {
        int row = wr + m * 16 + fr;
        ah8[m] = *(const i32x4*)(AI + row * 128 + ((g ^ (row & 7)) << 4));
        al8[m] = *(const i32x4*)(AI + row * 128 + (((4 | g) ^ (row & 7)) << 4));
      }
#pragma unroll
      for (int n = 0; n < 4; ++n) {
        int row = wc + n * 16 + fr;
        bh8[n] = *(const i32x4*)(BI + row * 128 + ((g ^ (row & 7)) << 4));
        bl8[n] = *(const i32x4*)(BI + row * 128 + (((4 | g) ^ (row & 7)) << 4));
      }
#pragma unroll
      for (int m = 0; m < 4; ++m)
#pragma unroll
        for (int n = 0; n < 4; ++n) {
          acc8[m][n] = __builtin_amdgcn_mfma_i32_16x16x64_i8(ah8[m], bl8[n],
                                                             acc8[m][n], 0, 0, 0);
          acc8[m][n] = __builtin_amdgcn_mfma_i32_16x16x64_i8(al8[m], bh8[n],
                                                             acc8[m][n], 0, 0, 0);
        }
    }
    __syncthreads();
  }

  // epilogue; C/D layout: col = lane&15, row = (lane>>4)*4 + reg  [m89]
  const int crow0 = m0 + wr + (lane >> 4) * 4;
  const int ccol0 = n0 + wc + fr;
#pragma unroll
  for (int m = 0; m < 4; ++m)
#pragma unroll
    for (int n = 0; n < 4; ++n)
#pragma unroll
      for (int j = 0; j < 4; ++j) {
        const int r = crow0 + m * 16 + j;
        const int cc = ccol0 + n * 16;
        float v = acc[m][n][j];
        if constexpr (MODE) v += C8 * (float)acc8[m][n][j];
        const long off = (long)b * sC_ + (long)r * N + cc;
        if constexpr (EPI == 0) {
          v += bias[cc];
          bf16 hi = (bf16)v;
          outQhi[off] = hi;
          float hf = (float)hi;
          outQhi8[off] = q8(hf, 127.f / RX);
          outQlo8[off] = q8(v - hf, 127.f * 512.f / RX);
        } else if constexpr (EPI == 1) {
          outF[off] = v > 0.f ? v : 0.f;
        } else {
          outF[off] = v;
        }
      }
}

// ---------------------------------------------------------------------------
// Row softmax (input already relu'd) + mask add, in place; also bf16 copy.
// ---------------------------------------------------------------------------
__global__ __launch_bounds__(256) void softmax_mask_k(
    float* __restrict__ U, const float* __restrict__ mask,
    bf16* __restrict__ Abf) {
  __shared__ float red[8];
  const long row = blockIdx.x;
  float* u = U + row * 2048;
  const float* mk = mask + row * 2048;
  bf16* ab = Abf + row * 2048;
  const int t = threadIdx.x;
  float4 v0 = *(const float4*)(u + t * 4);
  float4 v1 = *(const float4*)(u + 1024 + t * 4);
  float m = fmaxf(fmaxf(fmaxf(v0.x, v0.y), fmaxf(v0.z, v0.w)),
                  fmaxf(fmaxf(v1.x, v1.y), fmaxf(v1.z, v1.w)));
#pragma unroll
  for (int s = 32; s; s >>= 1) m = fmaxf(m, __shfl_xor(m, s));
  if ((t & 63) == 0) red[t >> 6] = m;
  __syncthreads();
  m = fmaxf(fmaxf(red[0], red[1]), fmaxf(red[2], red[3]));
  float e0 = __expf(v0.x - m), e1 = __expf(v0.y - m), e2 = __expf(v0.z - m),
        e3 = __expf(v0.w - m);
  float e4 = __expf(v1.x - m), e5 = __expf(v1.y - m), e6 = __expf(v1.z - m),
        e7 = __expf(v1.w - m);
  float s = ((e0 + e1) + (e2 + e3)) + ((e4 + e5) + (e6 + e7));
#pragma unroll
  for (int sh = 32; sh; sh >>= 1) s += __shfl_xor(s, sh);
  if ((t & 63) == 0) red[4 + (t >> 6)] = s;
  __syncthreads();
  s = (red[4] + red[5]) + (red[6] + red[7]);
  const float inv = 1.0f / s;
  float4 k0 = *(const float4*)(mk + t * 4);
  float4 k1 = *(const float4*)(mk + 1024 + t * 4);
  float4 a0 = {e0 * inv + k0.x, e1 * inv + k0.y, e2 * inv + k0.z,
               e3 * inv + k0.w};
  float4 a1 = {e4 * inv + k1.x, e5 * inv + k1.y, e6 * inv + k1.z,
               e7 * inv + k1.w};
  *(float4*)(u + t * 4) = a0;
  *(float4*)(u + 1024 + t * 4) = a1;
  bf16x4 b0 = {(bf16)a0.x, (bf16)a0.y, (bf16)a0.z, (bf16)a0.w};
  bf16x4 b1 = {(bf16)a1.x, (bf16)a1.y, (bf16)a1.z, (bf16)a1.w};
  *(bf16x4*)(ab + t * 4) = b0;
  *(bf16x4*)(ab + 1024 + t * 4) = b1;
}

// ---------------------------------------------------------------------------
extern "C" void kernel_launch(void* const* d_in, const int* in_sizes, int n_in,
                              void* d_out, int out_size, void* d_ws,
                              size_t ws_size, hipStream_t stream) {
  const float* X = (const float*)d_in[0];
  const float* mask = (const float*)d_in[1];
  const float* W = (const float*)d_in[2];
  const float* bias = (const float*)d_in[3];
  float* out_h = (float*)d_out;
  float* out_a = out_h + (size_t)Bb * Ll * Hh;

  const size_t NX = (size_t)Bb * Ll * Hh;  // 16,777,216
  const size_t NA = (size_t)Bb * Ll * Ll;  // 33,554,432
  const size_t NW = (size_t)Hh * Hh;       // 1,048,576
  bf16* Xhi = (bf16*)d_ws;
  bf16* XT = Xhi + NX;
  bf16* Qhi = XT + NX;
  bf16* Abf = Qhi + NX;
  bf16* Whi = Abf + NA;
  i8* Xhi8 = (i8*)(Whi + NW);
  i8* Xlo8 = Xhi8 + NX;
  i8* Qhi8 = Xlo8 + NX;
  i8* Qlo8 = Qhi8 + NX;
  i8* Whi8 = Qlo8 + NX;
  i8* Wlo8 = Whi8 + NW;
  // total ws: 239,075,328 bytes (same as previous round)

  const float C8_1 = (RX / 127.f) * (RW / 127.f) / 512.f;
  const float C8_2 = (RX / 127.f) * (RX / 127.f) / 512.f;

  split_x_k<<<dim3(Hh / 64, Ll / 64, Bb), 256, 0, stream>>>(X, Xhi, Xhi8,
                                                            Xlo8, XT);
  split_w_k<<<dim3((Hh * Hh / 4) / 256), 256, 0, stream>>>(W, Whi, Whi8, Wlo8);
  // GEMM1: Q = X W^T + b  (M=16384, N=1024, K=1024), bf16 hi*hi + i8 cross
  gemm_nt<0, 1><<<dim3(Hh / 128, (Bb * Ll) / 128, 1), 256, 0, stream>>>(
      Xhi, Xhi8, Xlo8, Whi, Whi8, Wlo8, Hh, Hh, 0, 0, 0, C8_1, nullptr, Qhi,
      Qhi8, Qlo8, bias);
  // GEMM2: U = relu(Q X^T) per batch (M=2048, N=2048, K=1024) -> out_a
  gemm_nt<1, 1><<<dim3(Ll / 128, Ll / 128, Bb), 256, 0, stream>>>(
      Qhi, Qhi8, Qlo8, Xhi, Xhi8, Xlo8, Ll, Hh, (long)Ll * Hh, (long)Ll * Hh,
      (long)Ll * Ll, C8_2, out_a, nullptr, nullptr, nullptr, nullptr);
  // softmax + mask, in place over out_a; bf16 copy to Abf
  softmax_mask_k<<<dim3(Bb * Ll), 256, 0, stream>>>(out_a, mask, Abf);
  // GEMM3: H = A X per batch (M=2048, N=1024, K=2048), plain bf16 NT vs X^T
  gemm_nt<2, 0><<<dim3(Hh / 128, Ll / 128, Bb), 256, 0, stream>>>(
      Abf, nullptr, nullptr, XT, nullptr, nullptr, Hh, Ll, (long)Ll * Ll,
      (long)Hh * Ll, (long)Ll * Hh, 0.f, out_h, nullptr, nullptr, nullptr,
      nullptr);
}